// Round 4
// baseline (523.555 us; speedup 1.0000x reference)
//
#include <hip/hip_runtime.h>
#include <stdint.h>

typedef __attribute__((ext_vector_type(8))) short short8;
typedef __attribute__((ext_vector_type(4))) float f32x4;
typedef __attribute__((ext_vector_type(4))) int i32x4;
typedef __attribute__((ext_vector_type(8))) unsigned short ushort8v;

#define NEGINF_F (-1000000.0f)
#define MFMA16 __builtin_amdgcn_mfma_f32_16x16x32_bf16

__device__ __forceinline__ unsigned short f2bf(float f) {
  union { float f; uint32_t u; } v; v.f = f;
  uint32_t r = (v.u + 0x7FFFu + ((v.u >> 16) & 1u)) >> 16;
  return (unsigned short)r;
}
__device__ __forceinline__ void gl_lds16(const void* g, void* l) {
  __builtin_amdgcn_global_load_lds(
      (const __attribute__((address_space(1))) void*)g,
      (__attribute__((address_space(3))) void*)l, 16, 0, 0);
}
#define BARRIER() asm volatile("s_barrier" ::: "memory")

// ---------------------------------------------------------------------------
// gemm256: C = A @ B^T (bf16 in, fp32 out, int mask -> NEGINF epilogue).
// 256x256 tile, BK=32, 512 thr = 8 waves (2M x 4N), per-wave 128x64 output.
// Deep pipeline: 4 LDS buffers (4 x 32KB = 128KB), 3 K-tiles prefetched
// ahead, COUNTED s_waitcnt vmcnt(12) at tile boundaries (never drains to 0
// in steady state -- T4; vmcnt retires in issue order, so vmcnt(12) waits
// exactly for the oldest tile's 4 loads). Raw s_barrier via asm (memory
// clobber) so the compiler's __syncthreads vmcnt(0) drain never appears.
// 2 phases/tile (n-frags 0,1 then 2,3) with setprio around MFMA clusters.
// BK=32 => 64B LDS rows => b128 frag reads are bank-balanced (no swizzle).
// Requires K % 32 == 0 and K/32 >= 4. Used for the scores GEMM (K=512).
// ---------------------------------------------------------------------------
__global__ __launch_bounds__(512, 1)
void gemm256(const unsigned short* __restrict__ A,
             const unsigned short* __restrict__ B,
             float* __restrict__ C, const int* __restrict__ mask,
             int K, int lda, int ldb, int ldc,
             long sA, long sB, long sC, long sM)
{
  __shared__ __align__(16) unsigned short lds[65536];   // 4 bufs x 16384 shorts

  const int t = threadIdx.x;
  const int b = blockIdx.z;
  const unsigned short* Ap = A + (long)b * sA;
  const unsigned short* Bp = B + (long)b * sB;
  const int* mp = mask + (long)b * sM;
  const int tm = blockIdx.x * 256;
  const int tn = blockIdx.y * 256;

  const int lane = t & 63, wave = t >> 6;
  const int wm = (wave >> 2) * 128;      // waves 0-3: rows 0-127; 4-7: 128-255
  const int wn = (wave & 3) * 64;        // 4 N-quarters
  const int q = lane >> 4, mr = lane & 15;

  f32x4 acc[8][4];
#pragma unroll
  for (int m = 0; m < 8; m++)
#pragma unroll
    for (int n = 0; n < 4; n++) acc[m][n] = (f32x4){0.f, 0.f, 0.f, 0.f};

  // staging: linear [row][k] bf16, row = t/4 (+128 on round 1), col = (t&3)*8
  const int srow = t >> 2;
  const int scol = (t & 3) * 8;

  auto stage = [&](int kt) {
    unsigned short* L = lds + (kt & 3) * 16384;
    const int k0 = kt << 5;
    const unsigned short* ga = Ap + (long)(tm + srow) * lda + k0 + scol;
    gl_lds16(ga,                  L + (size_t)t * 8);           // A rows 0-127
    gl_lds16(ga + (long)128 * lda, L + 4096 + (size_t)t * 8);   // A rows 128-255
    const unsigned short* gb = Bp + (long)(tn + srow) * ldb + k0 + scol;
    gl_lds16(gb,                  L + 8192 + (size_t)t * 8);    // B rows 0-127
    gl_lds16(gb + (long)128 * ldb, L + 12288 + (size_t)t * 8);  // B rows 128-255
  };

  auto compute = [&](int kt) {
    const unsigned short* LA = lds + (kt & 3) * 16384;
    const unsigned short* LB = LA + 8192;
    short8 af[8], b0, b1;
    // phase 0: A frags (reused by phase 1) + B n=0,1
#pragma unroll
    for (int m = 0; m < 8; m++)
      af[m] = *(const short8*)&LA[(size_t)(wm + m * 16 + mr) * 32 + q * 8];
    b0 = *(const short8*)&LB[(size_t)(wn + 0 * 16 + mr) * 32 + q * 8];
    b1 = *(const short8*)&LB[(size_t)(wn + 1 * 16 + mr) * 32 + q * 8];
    __builtin_amdgcn_s_setprio(1);
#pragma unroll
    for (int m = 0; m < 8; m++) acc[m][0] = MFMA16(af[m], b0, acc[m][0], 0, 0, 0);
#pragma unroll
    for (int m = 0; m < 8; m++) acc[m][1] = MFMA16(af[m], b1, acc[m][1], 0, 0, 0);
    __builtin_amdgcn_s_setprio(0);
    BARRIER();
    // phase 1: B n=2,3
    b0 = *(const short8*)&LB[(size_t)(wn + 2 * 16 + mr) * 32 + q * 8];
    b1 = *(const short8*)&LB[(size_t)(wn + 3 * 16 + mr) * 32 + q * 8];
    __builtin_amdgcn_s_setprio(1);
#pragma unroll
    for (int m = 0; m < 8; m++) acc[m][2] = MFMA16(af[m], b0, acc[m][2], 0, 0, 0);
#pragma unroll
    for (int m = 0; m < 8; m++) acc[m][3] = MFMA16(af[m], b1, acc[m][3], 0, 0, 0);
    __builtin_amdgcn_s_setprio(0);
  };

  const int NT = K >> 5;                 // 16 for K=512
  stage(0); stage(1); stage(2);          // 12 loads in flight

  for (int kt = 0; kt < NT - 3; ++kt) {
    stage(kt + 3);                                   // into buf (kt-1)&3: all
                                                     // waves passed last iter's
                                                     // trailing BARRIER
    asm volatile("s_waitcnt vmcnt(12)" ::: "memory");  // oldest tile (kt) done
    BARRIER();                                       // block-wide readiness
    compute(kt);
    BARRIER();                                       // protect buf before next
                                                     // iter's stage overwrites
  }
  asm volatile("s_waitcnt vmcnt(8)" ::: "memory");
  BARRIER(); compute(NT - 3); BARRIER();
  asm volatile("s_waitcnt vmcnt(4)" ::: "memory");
  BARRIER(); compute(NT - 2); BARRIER();
  asm volatile("s_waitcnt vmcnt(0)" ::: "memory");
  BARRIER(); compute(NT - 1);

  // epilogue: scalar mask + fp32 store (16-lane 64B segments)
  float* co = C + (long)b * sC;
#pragma unroll
  for (int m = 0; m < 8; m++) {
#pragma unroll
    for (int n = 0; n < 4; n++) {
      const int row0 = tm + wm + m * 16 + q * 4;
      const int col  = tn + wn + n * 16 + mr;
#pragma unroll
      for (int r = 0; r < 4; r++) {
        float x = acc[m][n][r];
        const long idx = (long)(row0 + r) * ldc + col;
        if (!mp[idx]) x = NEGINF_F;
        co[idx] = x;
      }
    }
  }
}

// ---------------------------------------------------------------------------
// 128x128 gemm_nt (round-3 version, unchanged): used for projections + z.
// ---------------------------------------------------------------------------
template<bool A32, bool OUT32, bool MASKED>
__global__ __launch_bounds__(256, A32 ? 2 : 4)
void gemm_nt(const void* __restrict__ Av, const unsigned short* __restrict__ B,
             void* __restrict__ Cv, const int* __restrict__ mask,
             int K, int lda, int ldb, int ldc,
             long sA, long sB, long sC, long sM, float scale)
{
  constexpr int ABYTES = A32 ? 128 * 32 * 4 : 128 * 32 * 2;
  constexpr int BBYTES = 128 * 32 * 2;
  constexpr int BUFB = ABYTES + BBYTES;
  __shared__ __align__(16) unsigned char smem[2 * BUFB];

  const int t = threadIdx.x;
  const int b = blockIdx.z;
  const float* Af = (const float*)Av + (long)b * sA;
  const unsigned short* Ah = (const unsigned short*)Av + (long)b * sA;
  const unsigned short* Bp = B + (long)b * sB;
  const int* mp = MASKED ? (mask + (long)b * sM) : nullptr;
  const int tm = blockIdx.x * 128;
  const int tn = blockIdx.y * 128;

  const int lane = t & 63, wave = t >> 6;
  const int wm = (wave & 1) * 64, wn = (wave >> 1) * 64;
  const int q = lane >> 4, mr = lane & 15;

  f32x4 acc[4][4];
#pragma unroll
  for (int i = 0; i < 4; i++)
#pragma unroll
    for (int j = 0; j < 4; j++) acc[i][j] = (f32x4){0.f, 0.f, 0.f, 0.f};

  const int r0a = t >> 2;
  const int cswz = ((t & 3) ^ ((t >> 2) & 3)) * 8;
  const int sw8 = (q ^ (mr & 3)) * 8;

  auto stage = [&](int buf, int k0) {
    unsigned char* base = smem + buf * BUFB;
    if (A32) {
      float* Asf = (float*)base;
#pragma unroll
      for (int rd = 0; rd < 4; rd++) {
        const int f = rd * 1024 + t * 4;
        const int row = f >> 5, col = f & 31;
        gl_lds16(Af + (long)(tm + row) * lda + k0 + col, Asf + f);
      }
    } else {
      unsigned short* Ash = (unsigned short*)base;
      const unsigned short* ga = Ah + (long)(tm + r0a) * lda + k0 + cswz;
      gl_lds16(ga, &Ash[(size_t)t * 8]);
      gl_lds16(ga + (long)64 * lda, &Ash[(size_t)(t + 256) * 8]);
    }
    unsigned short* Bsb = (unsigned short*)(base + ABYTES);
    const unsigned short* gb = Bp + (long)(tn + r0a) * ldb + k0 + cswz;
    gl_lds16(gb, &Bsb[(size_t)t * 8]);
    gl_lds16(gb + (long)64 * ldb, &Bsb[(size_t)(t + 256) * 8]);
  };

  const int nt = K >> 5;
  stage(0, 0);
  __syncthreads();

  for (int ti = 0; ti < nt; ++ti) {
    if (ti + 1 < nt) stage((ti + 1) & 1, (ti + 1) << 5);

    const unsigned char* base = smem + (ti & 1) * BUFB;
    const unsigned short* Bs = (const unsigned short*)(base + ABYTES);
    short8 af[4], bfr[4];
#pragma unroll
    for (int i = 0; i < 4; i++) {
      if (A32) {
        const float* Asf = (const float*)base;
        const int fb = (wm + i * 16 + mr) * 32 + q * 8;
        const f32x4 x0 = *(const f32x4*)&Asf[fb];
        const f32x4 x1 = *(const f32x4*)&Asf[fb + 4];
        short8 v;
        v[0] = (short)f2bf(x0[0]); v[1] = (short)f2bf(x0[1]);
        v[2] = (short)f2bf(x0[2]); v[3] = (short)f2bf(x0[3]);
        v[4] = (short)f2bf(x1[0]); v[5] = (short)f2bf(x1[1]);
        v[6] = (short)f2bf(x1[2]); v[7] = (short)f2bf(x1[3]);
        af[i] = v;
      } else {
        const unsigned short* Ash = (const unsigned short*)base;
        af[i] = *(const short8*)&Ash[(size_t)(wm + i * 16 + mr) * 32 + sw8];
      }
      bfr[i] = *(const short8*)&Bs[(size_t)(wn + i * 16 + mr) * 32 + sw8];
    }
#pragma unroll
    for (int i = 0; i < 4; i++)
#pragma unroll
      for (int j = 0; j < 4; j++)
        acc[i][j] = MFMA16(af[i], bfr[j], acc[i][j], 0, 0, 0);

    if (ti + 1 < nt) __syncthreads();
  }

  if (OUT32) {
    float* ep = (float*)smem;
    float* co = (float*)Cv + (long)b * sC;
    const int band = wm >> 2;
    const int tr = t >> 3;
    const int tcb = (t & 7) * 16;
    const int growb = tm + (tr >> 4) * 64 + (tr & 15);
#pragma unroll
    for (int i = 0; i < 4; i++) {
      __syncthreads();
#pragma unroll
      for (int j = 0; j < 4; j++) {
        const int colb = wn + j * 16 + mr;
#pragma unroll
        for (int r = 0; r < 4; r++) {
          const int lr = band + q * 4 + r;
          ep[lr * 128 + ((colb + lr * 4) & 127)] = acc[i][j][r];
        }
      }
      __syncthreads();
      const int gr = growb + i * 16;
      const long rbase = (long)gr * ldc;
      const float* eprow = ep + tr * 128;
      const int rot = tr * 4;
#pragma unroll
      for (int k = 0; k < 4; k++) {
        const int lc = tcb + k * 4;
        f32x4 x = *(const f32x4*)&eprow[(lc + rot) & 127];
        x *= scale;
        if (MASKED) {
          const i32x4 mv = *(const i32x4*)&mp[rbase + tn + lc];
#pragma unroll
          for (int e = 0; e < 4; e++)
            if (!mv[e]) x[e] = NEGINF_F;
        }
        *(f32x4*)&co[rbase + tn + lc] = x;
      }
    }
  } else {
#pragma unroll
    for (int i = 0; i < 4; i++) {
#pragma unroll
      for (int j = 0; j < 4; j++) {
        const int row0 = tm + wm + i * 16 + q * 4;
        const int col  = tn + wn + j * 16 + mr;
        const f32x4 v = acc[i][j];
#pragma unroll
        for (int r = 0; r < 4; r++) {
          float x = v[r] * scale;
          ((unsigned short*)Cv + (long)b * sC)[(long)(row0 + r) * ldc + col] = f2bf(x);
        }
      }
    }
  }
}

// one block per row of 2048 fp32: max -> sumexp -> normalize, in place.
// Optionally also emits the normalized row as bf16 to Pb (for the z GEMM).
__global__ __launch_bounds__(256) void softmax_rows_f32(
    float* __restrict__ P, unsigned short* __restrict__ Pb)
{
  const int row = blockIdx.x;
  float* p = P + (size_t)row * 2048;
  const int t = threadIdx.x, lane = t & 63, wv = t >> 6;
  f32x4 a = *(const f32x4*)(p + t * 8);
  f32x4 c = *(const f32x4*)(p + t * 8 + 4);
  float x[8] = {a[0], a[1], a[2], a[3], c[0], c[1], c[2], c[3]};
  float mx = x[0];
#pragma unroll
  for (int j = 1; j < 8; j++) mx = fmaxf(mx, x[j]);
#pragma unroll
  for (int o = 32; o > 0; o >>= 1) mx = fmaxf(mx, __shfl_xor(mx, o));
  __shared__ float rm[4], rs[4];
  if (lane == 0) rm[wv] = mx;
  __syncthreads();
  mx = fmaxf(fmaxf(rm[0], rm[1]), fmaxf(rm[2], rm[3]));
  float e[8], s = 0.f;
#pragma unroll
  for (int j = 0; j < 8; j++) { e[j] = __expf(x[j] - mx); s += e[j]; }
#pragma unroll
  for (int o = 32; o > 0; o >>= 1) s += __shfl_xor(s, o);
  if (lane == 0) rs[wv] = s;
  __syncthreads();
  s = rs[0] + rs[1] + rs[2] + rs[3];
  const float linv = (mx < -1.0e5f) ? 0.f : 1.f / s;
  f32x4 o0 = {e[0] * linv, e[1] * linv, e[2] * linv, e[3] * linv};
  f32x4 o1 = {e[4] * linv, e[5] * linv, e[6] * linv, e[7] * linv};
  *(f32x4*)(p + t * 8) = o0;
  *(f32x4*)(p + t * 8 + 4) = o1;
  if (Pb) {
    ushort8v ob;
    ob[0] = f2bf(o0[0]); ob[1] = f2bf(o0[1]); ob[2] = f2bf(o0[2]); ob[3] = f2bf(o0[3]);
    ob[4] = f2bf(o1[0]); ob[5] = f2bf(o1[1]); ob[6] = f2bf(o1[2]); ob[7] = f2bf(o1[3]);
    *(ushort8v*)(Pb + (size_t)row * 2048 + t * 8) = ob;
  }
}

// triple fp32 -> bf16 bulk convert (3 x 8388608 elems, blockIdx.y selects)
__global__ __launch_bounds__(256) void cvt3(
    const float* __restrict__ s0, unsigned short* __restrict__ d0,
    const float* __restrict__ s1, unsigned short* __restrict__ d1,
    const float* __restrict__ s2, unsigned short* __restrict__ d2)
{
  const float* s = blockIdx.y == 0 ? s0 : (blockIdx.y == 1 ? s1 : s2);
  unsigned short* d = blockIdx.y == 0 ? d0 : (blockIdx.y == 1 ? d1 : d2);
  const size_t i = ((size_t)blockIdx.x * 256 + threadIdx.x) * 8;
  const float4 a = *(const float4*)(s + i);
  const float4 b = *(const float4*)(s + i + 4);
  ushort8v o;
  o[0] = f2bf(a.x); o[1] = f2bf(a.y); o[2] = f2bf(a.z); o[3] = f2bf(a.w);
  o[4] = f2bf(b.x); o[5] = f2bf(b.y); o[6] = f2bf(b.z); o[7] = f2bf(b.w);
  *(ushort8v*)(d + i) = o;
}

// per-batch transpose+convert: src[b][s][i] fp32 (2048x512) -> dst[b][i][s] bf16
// (only used on the !use_pb fallback path)
__global__ __launch_bounds__(256) void cvt_t_v(
    const float* __restrict__ src, unsigned short* __restrict__ dst)
{
  const int b = blockIdx.z;
  __shared__ float tile[32][33];
  const int s0 = blockIdx.x * 32, i0 = blockIdx.y * 32;
  const int tx = threadIdx.x & 31, ty = threadIdx.x >> 5;
#pragma unroll
  for (int r = 0; r < 4; r++) {
    const int srow = ty + r * 8;
    tile[srow][tx] = src[((size_t)b * 2048 + s0 + srow) * 512 + i0 + tx];
  }
  __syncthreads();
#pragma unroll
  for (int r = 0; r < 4; r++) {
    const int irow = ty + r * 8;
    dst[((size_t)b * 512 + i0 + irow) * 2048 + s0 + tx] = f2bf(tile[tx][irow]);
  }
}

// 512x512 transpose + fp32->bf16 (x3 weights) so projections run as NT GEMMs.
__global__ __launch_bounds__(256) void transpose_w(
    const float* __restrict__ W0, const float* __restrict__ W1,
    const float* __restrict__ W2,
    unsigned short* __restrict__ T0, unsigned short* __restrict__ T1,
    unsigned short* __restrict__ T2)
{
  const float* W = blockIdx.z == 0 ? W0 : (blockIdx.z == 1 ? W1 : W2);
  unsigned short* T = blockIdx.z == 0 ? T0 : (blockIdx.z == 1 ? T1 : T2);
  __shared__ float tile[32][33];
  const int bx = blockIdx.x * 32, by = blockIdx.y * 32;
  const int tx = threadIdx.x & 31, ty = threadIdx.x >> 5;
#pragma unroll
  for (int i = 0; i < 4; i++) {
    const int r = ty + i * 8;
    tile[r][tx] = W[(size_t)(by + r) * 512 + bx + tx];
  }
  __syncthreads();
#pragma unroll
  for (int i = 0; i < 4; i++) {
    const int r = ty + i * 8;
    T[(size_t)(bx + r) * 512 + by + tx] = f2bf(tile[tx][r]);
  }
}

extern "C" void kernel_launch(void* const* d_in, const int* in_sizes, int n_in,
                              void* d_out, int out_size, void* d_ws, size_t ws_size,
                              hipStream_t stream) {
  const float* Xq = (const float*)d_in[0];
  const float* Xk = (const float*)d_in[1];
  const float* Xv = (const float*)d_in[2];
  const int*   mk = (const int*)d_in[3];
  const float* Wq = (const float*)d_in[4];
  const float* Wk = (const float*)d_in[5];
  const float* Wv = (const float*)d_in[6];

  float* z = (float*)d_out;                          // [8,2048,512] fp32
  float* P = z + (size_t)8 * 2048 * 512;             // [8,2048,2048] fp32

  unsigned short* w    = (unsigned short*)d_ws;
  unsigned short* Wtq  = w;
  unsigned short* Wtk  = w + 262144;
  unsigned short* Wtv  = w + 524288;
  unsigned short* buf1 = w + 786432;                 // 8388608 elems
  unsigned short* buf2 = buf1 + 8388608;
  unsigned short* Ks   = buf2 + 8388608;
  unsigned short* Pb   = Ks;                         // overlay, 33554432 elems
  const bool use_pb = ws_size >= (size_t)102236160;

  // scratch overlays in d_out regions that are written later:
  unsigned short* Xkb = (unsigned short*)P;          // first 16.8MB of P
  unsigned short* Xvb = (unsigned short*)z;          // first 16.8MB of z

  const float inv_scale = 0.21022410381342863f;      // 512^-0.25

  transpose_w<<<dim3(16, 16, 3), 256, 0, stream>>>(Wq, Wk, Wv, Wtq, Wtk, Wtv);

  // Xq -> buf1, Xk -> Xkb, Xv -> Xvb (bf16) in one launch
  cvt3<<<dim3(4096, 3), 256, 0, stream>>>(Xq, buf1, Xk, Xkb, Xv, Xvb);

  // Q projection: bf16(Xq) @ Wq -> buf2 (Qs bf16, scaled)
  gemm_nt<false, false, false><<<dim3(128, 4, 1), 256, 0, stream>>>(
      buf1, Wtq, buf2, nullptr, 512, 512, 512, 512, 0, 0, 0, 0, inv_scale);

  // K projection -> Ks (bf16, scaled)
  gemm_nt<false, false, false><<<dim3(128, 4, 1), 256, 0, stream>>>(
      Xkb, Wtk, Ks, nullptr, 512, 512, 512, 512, 0, 0, 0, 0, inv_scale);

  // Scores: per batch Qs_b @ Ks_b^T, mask epilogue -> P (fp32 logits)
  // 256x256 deep-pipelined kernel, grid 8x8x8 = 512 blocks.
  gemm256<<<dim3(8, 8, 8), 512, 0, stream>>>(
      buf2, Ks, P, mk, 512, 512, 512, 2048,
      1048576, 1048576, 4194304, 4194304);

  softmax_rows_f32<<<dim3(16384), 256, 0, stream>>>(P, use_pb ? Pb : nullptr);

  if (use_pb) {
    // E-route: Vw^T[b][e][s] = sum_i Wtv[e][i] * Xvb[b][s][i]  (= (Xv@Wv)^T)
    // A = Wtv (batch-stride 0), B = Xvb, C = buf2 (Qs dead after scores).
    gemm_nt<false, false, false><<<dim3(4, 16, 8), 256, 0, stream>>>(
        Wtv, Xvb, buf2, nullptr, 512, 512, 512, 2048,
        0, 1048576, 1048576, 0, 1.0f);
    // z[b][q][e] = sum_s Pb[b][q][s] * Vw^T[b][e][s]   (fp32 out)
    gemm_nt<false, true, false><<<dim3(16, 4, 8), 256, 0, stream>>>(
        Pb, buf2, z, nullptr, 2048, 2048, 2048, 512,
        4194304, 1048576, 1048576, 0, 1.0f);
  } else {
    // fallback: old chain (A32 PV + z GEMM)
    cvt_t_v<<<dim3(64, 16, 8), 256, 0, stream>>>(Xv, buf1);
    gemm_nt<true, false, false><<<dim3(16, 4, 8), 256, 0, stream>>>(
        P, buf1, buf2, nullptr, 2048, 2048, 2048, 512,
        4194304, 1048576, 1048576, 0, 1.0f);
    gemm_nt<false, true, false><<<dim3(128, 4, 1), 256, 0, stream>>>(
        buf2, Wtv, z, nullptr, 512, 512, 512, 512, 0, 0, 0, 0, 1.0f);
  }
}